// Round 8
// baseline (3016.936 us; speedup 1.0000x reference)
//
#include <hip/hip_runtime.h>
#include <hip/hip_bf16.h>

#define BB 512
#define TT 128
#define DD 128
#define HH 128
#define EPSV 1e-6f

typedef _Float16 f16x2 __attribute__((ext_vector_type(2)));
typedef unsigned u32;

__device__ __forceinline__ float dot2f(u32 a, u32 b, float c) {
#if __has_builtin(__builtin_amdgcn_fdot2)
    return __builtin_amdgcn_fdot2(__builtin_bit_cast(f16x2, a),
                                  __builtin_bit_cast(f16x2, b), c, false);
#else
    f16x2 fa = __builtin_bit_cast(f16x2, a);
    f16x2 fb = __builtin_bit_cast(f16x2, b);
    return fmaf((float)fa.y, (float)fb.y, fmaf((float)fa.x, (float)fb.x, c));
#endif
}

__device__ __forceinline__ u32 pkh(float a, float b) {
    f16x2 v; v.x = (_Float16)a; v.y = (_Float16)b;
    return __builtin_bit_cast(u32, v);
}
__device__ __forceinline__ float2 uph(u32 u) {
    f16x2 v = __builtin_bit_cast(f16x2, u);
    return make_float2((float)v.x, (float)v.y);
}
__device__ __forceinline__ float bflo(u32 u) { return __builtin_bit_cast(float, u << 16); }
__device__ __forceinline__ float bfhi(u32 u) { return __builtin_bit_cast(float, u & 0xffff0000u); }
__device__ __forceinline__ float sigm(float x) { return 1.f / (1.f + __expf(-x)); }
__device__ __forceinline__ float tanhfast(float x) {
    float t = __expf(2.f * x);
    return 1.f - 2.f / (t + 1.f);
}

// ---------------- denom per timestep (float4) ----------------
__global__ __launch_bounds__(256) void k_denom(const float* __restrict__ masks,
                                               float* __restrict__ invden) {
    int t = blockIdx.x;
    float s = 0.f;
    for (int idx = threadIdx.x; idx < BB * 32; idx += 256) {
        int b = idx >> 5, q = idx & 31;
        float4 v = *(const float4*)(masks + ((size_t)b * TT + t) * DD + q * 4);
        s += v.x + v.y + v.z + v.w;
    }
    __shared__ float red[256];
    red[threadIdx.x] = s;
    __syncthreads();
    for (int off = 128; off > 0; off >>= 1) {
        if (threadIdx.x < off) red[threadIdx.x] += red[threadIdx.x + off];
        __syncthreads();
    }
    if (threadIdx.x == 0) invden[t] = 1.f / (red[0] + EPSV);
}

// ---------------- pack all weights to fp16 pairs ----------------
// wp2 (gates, 98304 u32): thread tid1024=(kq*128+n4) of k_rnn3 loads 24 uint4
//   chunks: u32 flat = (i*1024 + tid)*4 + c -> pair of W3[2*(kq*24+i)][n4*4+c]
//   W3: k<128 -> Wk[k] (c_c); k<256 -> Wr[k-128] (h); else Wk[k-128] (m)
// wpre1 (16384 u32): [k2][c]: c<128 -> Wth row c, else Wtx row c-128 (pairs over k)
// wpre2 (16384 u32): [kh][k2][c]: Wwc rows kh*128+2k2, +1, col c
__global__ __launch_bounds__(256) void k_pack2(const float* __restrict__ Wk,
                                               const float* __restrict__ Wr,
                                               const float* __restrict__ Wth,
                                               const float* __restrict__ Wtx,
                                               const float* __restrict__ Wwc,
                                               u32* __restrict__ wp2) {
    int idx = blockIdx.x * 256 + threadIdx.x;     // 131072 total
    if (idx < 98304) {
        int c = idx & 3;
        int t = (idx >> 2) & 1023;
        int i = idx >> 12;
        int kq = t >> 7, n4 = t & 127;
        int k0 = 2 * (kq * 24 + i);
        int n = n4 * 4 + c;
        float w0, w1;
        {
            int k = k0;
            w0 = (k < 128) ? Wk[(size_t)k * 512 + n]
               : (k < 256) ? Wr[(size_t)(k - 128) * 512 + n]
                           : Wk[(size_t)(k - 128) * 512 + n];
            k = k0 + 1;
            w1 = (k < 128) ? Wk[(size_t)k * 512 + n]
               : (k < 256) ? Wr[(size_t)(k - 128) * 512 + n]
                           : Wk[(size_t)(k - 128) * 512 + n];
        }
        wp2[idx] = pkh(w0, w1);
    } else if (idx < 114688) {
        int p = idx - 98304;
        int k2 = p >> 8, c = p & 255;
        const float* Wsrc = (c < 128) ? (Wth + (size_t)c * DD) : (Wtx + (size_t)(c - 128) * DD);
        wp2[idx] = pkh(Wsrc[2 * k2], Wsrc[2 * k2 + 1]);
    } else {
        int p = idx - 114688;
        int kh = p >> 13, k2 = (p >> 7) & 63, c = p & 127;
        int r = kh * 128 + 2 * k2;
        wp2[idx] = pkh(Wwc[(size_t)r * DD + c], Wwc[(size_t)(r + 1) * DD + c]);
    }
}

// ---------------- precompute gammaH, beta (fp16 dot2, reg-resident W) ----------------
__global__ __launch_bounds__(256) void k_pre2(
    const float* __restrict__ masks, const float* __restrict__ deltas,
    const float* __restrict__ bth, const float* __restrict__ btx,
    const float* __restrict__ bwc,
    const u32* __restrict__ wpre1, const u32* __restrict__ wpre2,
    __hip_bfloat16* __restrict__ gH, __hip_bfloat16* __restrict__ beta) {

    __shared__ __align__(16) u32 dp[32][64];
    __shared__ __align__(16) u32 mp[32][64];
    __shared__ __align__(16) u32 gxp[32][64];
    __shared__ __align__(16) float bpart[32][128];

    const int tid = threadIdx.x;
    const int r0 = blockIdx.x * 32;

    for (int p = tid; p < 2048; p += 256) {
        int r = p >> 6, k2 = p & 63;
        float2 dv = *(const float2*)(deltas + (size_t)(r0 + r) * DD + 2 * k2);
        float2 mv = *(const float2*)(masks + (size_t)(r0 + r) * DD + 2 * k2);
        dp[r][k2] = pkh(dv.x, dv.y);
        mp[r][k2] = pkh(mv.x, mv.y);
    }
    __syncthreads();

    // ---- stage 1: gammaH (c<128) / gamma_x (c>=128) ----
    {
        const int c = tid;
        u32 wreg[64];
#pragma unroll
        for (int k2 = 0; k2 < 64; ++k2) wreg[k2] = wpre1[k2 * 256 + c];
        const float bias = (c < 128) ? bth[c] : btx[c - 128];
        for (int half = 0; half < 2; ++half) {
            float acc[16];
#pragma unroll
            for (int rr = 0; rr < 16; ++rr) acc[rr] = 0.f;
#pragma unroll
            for (int k4 = 0; k4 < 16; ++k4) {
#pragma unroll
                for (int rr = 0; rr < 16; ++rr) {
                    uint4 dv = *(const uint4*)&dp[half * 16 + rr][k4 * 4];
                    acc[rr] = dot2f(dv.x, wreg[k4 * 4 + 0], acc[rr]);
                    acc[rr] = dot2f(dv.y, wreg[k4 * 4 + 1], acc[rr]);
                    acc[rr] = dot2f(dv.z, wreg[k4 * 4 + 2], acc[rr]);
                    acc[rr] = dot2f(dv.w, wreg[k4 * 4 + 3], acc[rr]);
                }
            }
#pragma unroll
            for (int rr = 0; rr < 16; ++rr) {
                int r = half * 16 + rr;
                float v = __expf(-fmaxf(acc[rr] + bias, 0.f));
                if (c < 128) gH[(size_t)(r0 + r) * DD + c] = __float2bfloat16(v);
                float vo = __shfl_xor(v, 1);
                if (c >= 128 && !(c & 1)) gxp[r][(c - 128) >> 1] = pkh(v, vo);
            }
        }
    }
    __syncthreads();

    // ---- stage 2: beta = [gamma_x; m] @ Wwc ----
    {
        const int c2 = tid & 127, kh = tid >> 7;
        u32 wreg[64];
#pragma unroll
        for (int k2 = 0; k2 < 64; ++k2) wreg[k2] = wpre2[kh * 8192 + k2 * 128 + c2];
        const float bb = bwc[c2];
        const u32 (*inp)[64] = kh ? mp : gxp;
        for (int half = 0; half < 2; ++half) {
            float acc[16];
#pragma unroll
            for (int rr = 0; rr < 16; ++rr) acc[rr] = 0.f;
#pragma unroll
            for (int k4 = 0; k4 < 16; ++k4) {
#pragma unroll
                for (int rr = 0; rr < 16; ++rr) {
                    uint4 dv = *(const uint4*)&inp[half * 16 + rr][k4 * 4];
                    acc[rr] = dot2f(dv.x, wreg[k4 * 4 + 0], acc[rr]);
                    acc[rr] = dot2f(dv.y, wreg[k4 * 4 + 1], acc[rr]);
                    acc[rr] = dot2f(dv.z, wreg[k4 * 4 + 2], acc[rr]);
                    acc[rr] = dot2f(dv.w, wreg[k4 * 4 + 3], acc[rr]);
                }
            }
            if (kh == 1) {
#pragma unroll
                for (int rr = 0; rr < 16; ++rr) bpart[half * 16 + rr][c2] = acc[rr];
            }
            __syncthreads();
            if (kh == 0) {
#pragma unroll
                for (int rr = 0; rr < 16; ++rr) {
                    int r = half * 16 + rr;
                    beta[(size_t)(r0 + r) * DD + c2] =
                        __float2bfloat16(acc[rr] + bpart[r][c2] + bb);
                }
            }
        }
    }
}

// ---------------- recurrent kernel: 256 blocks x 2 rows x 1024 threads ----------------
__global__ __launch_bounds__(1024, 4) void k_rnn3(
    const float* __restrict__ values, const float* __restrict__ masks,
    const float* __restrict__ Whr, const float* __restrict__ bhr,
    const float* __restrict__ Wfr, const float* __restrict__ bfr,
    const float* __restrict__ bl,
    const float* __restrict__ Wd, const float* __restrict__ bd,
    const float* __restrict__ Wo, const float* __restrict__ bo,
    const float* __restrict__ invden,
    const __hip_bfloat16* __restrict__ gHws, const __hip_bfloat16* __restrict__ betws,
    const u32* __restrict__ wp2,
    float* __restrict__ out)
{
    const int tid = threadIdx.x;
    const int lane = tid & 63;
    const int w = tid >> 6;
    const int b0 = blockIdx.x * 2;

    __shared__ __align__(16) u32 whr2[128][68];
    __shared__ __align__(16) u32 wfr2[128][68];
    __shared__ __align__(16) u32 ag2[2][192];   // [0..64)=c_c, [64..128)=h, [128..192)=m  (fp16 pairs)
    __shared__ __align__(16) u32 xc2[2][64];
    __shared__ __align__(16) float gp[8][2][512];
    __shared__ __align__(16) float xS[2][2][128], mS[2][2][128];
    __shared__ __align__(16) u32 betS[2][2][64], ghS[2][2][64];
    __shared__ float blS[512];
    __shared__ float invdS[128], bhrS[128], bfrS[128];
    __shared__ float slots1[16], slots2[16];
    __shared__ float lossAcc[2];
    __shared__ float predS[4];

    // ---- gates weights into registers (96 u32 fp16 pairs) ----
    u32 wr_[96];
    {
        const uint4* wp4 = (const uint4*)wp2;
#pragma unroll
        for (int i = 0; i < 24; ++i) {
            uint4 q = wp4[i * 1024 + tid];
            wr_[i * 4 + 0] = q.x; wr_[i * 4 + 1] = q.y;
            wr_[i * 4 + 2] = q.z; wr_[i * 4 + 3] = q.w;
        }
    }
    // ---- stage Whr / Wfr as fp16 k-pairs in LDS ----
    for (int idx = tid; idx < 8192; idx += 1024) {
        int k2 = idx >> 7, j = idx & 127;
        whr2[j][k2] = pkh(Whr[(size_t)(2 * k2) * DD + j], Whr[(size_t)(2 * k2 + 1) * DD + j]);
    }
    for (int idx = tid; idx < 8192; idx += 1024) {
        int j = idx >> 6, k2 = idx & 63;
        float2 wv = *(const float2*)&Wfr[(size_t)j * DD + 2 * k2];
        wfr2[j][k2] = pkh(wv.x, wv.y);
    }
    if (tid < 512) blS[tid] = bl[tid];
    if (tid < 128) { invdS[tid] = invden[tid]; bhrS[tid] = bhr[tid]; bfrS[tid] = bfr[tid]; }
    if (tid < 2) lossAcc[tid] = 0.f;
    // initial stream load (t=0) + state init
    if (tid < 128) {
        int prow = tid >> 6, pj2 = tid & 63;
        size_t r2 = ((size_t)(b0 + prow) * TT + 0) * DD + 2 * pj2;
        float2 px = *(const float2*)(values + r2);
        float2 pm = *(const float2*)(masks + r2);
        u32 pb = *(const u32*)(betws + r2);
        u32 pg = *(const u32*)(gHws + r2);
        *(float2*)&xS[0][prow][2 * pj2] = px;
        *(float2*)&mS[0][prow][2 * pj2] = pm;
        betS[0][prow][pj2] = pb;
        ghS[0][prow][pj2] = pg;
        ag2[prow][128 + pj2] = pkh(pm.x, pm.y);   // m pairs for t=0 gates
        ag2[prow][64 + pj2] = 0u;                 // h = 0 (already "decayed")
    }
    float cs = 0.f;                               // c state (tid<256 threads own it)
    __syncthreads();

    // GEMV coords: 16 waves: row = w>>3, jb = w&7, j = jb*16 + (lane&15), kq = lane>>4
    const int grow = w >> 3, jb = w & 7;
    const int jj = lane & 15, kq = lane >> 4;
    const int j = jb * 16 + jj;

    for (int t = 0; t < TT; ++t) {
        const int cur = t & 1, nxt = cur ^ 1;
        float xhat = 0.f;

        // ---- PH_A: xhat = h @ Whr (+pw1) ----
        {
            const uint4* wrp = (const uint4*)&whr2[j][kq * 16];
            const uint4* hap = (const uint4*)&ag2[grow][64 + kq * 16];
            float s = 0.f;
#pragma unroll
            for (int c4 = 0; c4 < 4; ++c4) {
                uint4 wv = wrp[c4]; uint4 av = hap[c4];
                s = dot2f(av.x, wv.x, s); s = dot2f(av.y, wv.y, s);
                s = dot2f(av.z, wv.z, s); s = dot2f(av.w, wv.w, s);
            }
            s += __shfl_xor(s, 16);
            s += __shfl_xor(s, 32);
            float xcv = 0.f;
            if (lane < 16) {
                xhat = s + bhrS[j];
                float x = xS[cur][grow][j], m = mS[cur][grow][j];
                xcv = m * x + (1.f - m) * xhat;
                float l = fabsf(x - xhat) * m;
                l += __shfl_xor(l, 8); l += __shfl_xor(l, 4);
                l += __shfl_xor(l, 2); l += __shfl_xor(l, 1);
                if (lane == 0) slots1[w] = l;
            }
            float xo = __shfl(xcv, 2 * (lane & 7));
            float xo2 = __shfl(xcv, 2 * (lane & 7) + 1);
            if (lane < 8) xc2[grow][jb * 8 + lane] = pkh(xo, xo2);
        }
        __syncthreads();

        // ---- PH_B: zhat = x_c @ Wfr^T (+pw2, imputation) ----
        {
            const uint4* wfp = (const uint4*)&wfr2[j][kq * 16];
            const uint4* xap = (const uint4*)&xc2[grow][kq * 16];
            float s = 0.f;
#pragma unroll
            for (int c4 = 0; c4 < 4; ++c4) {
                uint4 wv = wfp[c4]; uint4 av = xap[c4];
                s = dot2f(av.x, wv.x, s); s = dot2f(av.y, wv.y, s);
                s = dot2f(av.z, wv.z, s); s = dot2f(av.w, wv.w, s);
            }
            s += __shfl_xor(s, 16);
            s += __shfl_xor(s, 32);
            float ccv = 0.f;
            if (lane < 16) {
                float z = s + bfrS[j];
                u32 bu = betS[cur][grow][j >> 1];
                float be = (j & 1) ? bfhi(bu) : bflo(bu);
                float ch = be * z + (1.f - be) * xhat;
                float x = xS[cur][grow][j], m = mS[cur][grow][j];
                float l = (fabsf(x - z) + fabsf(x - ch)) * m;
                ccv = m * x + (1.f - m) * ch;
                out[512 + ((size_t)(b0 + grow) * TT + t) * DD + j] = ccv;
                l += __shfl_xor(l, 8); l += __shfl_xor(l, 4);
                l += __shfl_xor(l, 2); l += __shfl_xor(l, 1);
                if (lane == 0) slots2[w] = l;
            }
            float co = __shfl(ccv, 2 * (lane & 7));
            float co2 = __shfl(ccv, 2 * (lane & 7) + 1);
            if (lane < 8) ag2[grow][jb * 8 + lane] = pkh(co, co2);
        }
        __syncthreads();

        // ---- PH_C: gates partials + stream prefetch (issue early, write late) ----
        {
            float2 px, pm; u32 pb = 0, pg = 0;
            int prow = tid >> 6, pj2 = tid & 63;
            if (tid < 128) {
                int tc = (t + 1 < TT) ? t + 1 : TT - 1;
                size_t r2 = ((size_t)(b0 + prow) * TT + tc) * DD + 2 * pj2;
                px = *(const float2*)(values + r2);
                pm = *(const float2*)(masks + r2);
                pb = *(const u32*)(betws + r2);
                pg = *(const u32*)(gHws + r2);
            }
            const int ckq = tid >> 7, cn4 = tid & 127;
            float a0[4], a1[4];
#pragma unroll
            for (int c = 0; c < 4; ++c) { a0[c] = 0.f; a1[c] = 0.f; }
            const uint4* g0 = (const uint4*)&ag2[0][ckq * 24];
            const uint4* g1 = (const uint4*)&ag2[1][ckq * 24];
#pragma unroll
            for (int i = 0; i < 6; ++i) {
                uint4 qa = g0[i]; uint4 qb = g1[i];
#define GST(AV, BV, E)                                               \
                {                                                    \
                    _Pragma("unroll")                                \
                    for (int c = 0; c < 4; ++c) {                    \
                        u32 wv = wr_[(i * 4 + (E)) * 4 + c];         \
                        a0[c] = dot2f((AV), wv, a0[c]);              \
                        a1[c] = dot2f((BV), wv, a1[c]);              \
                    }                                                \
                }
                GST(qa.x, qb.x, 0)
                GST(qa.y, qb.y, 1)
                GST(qa.z, qb.z, 2)
                GST(qa.w, qb.w, 3)
#undef GST
            }
            *(float4*)&gp[ckq][0][cn4 * 4] = make_float4(a0[0], a0[1], a0[2], a0[3]);
            *(float4*)&gp[ckq][1][cn4 * 4] = make_float4(a1[0], a1[1], a1[2], a1[3]);
            if (tid < 128) {
                *(float2*)&xS[nxt][prow][2 * pj2] = px;
                *(float2*)&mS[nxt][prow][2 * pj2] = pm;
                betS[nxt][prow][pj2] = pb;
                ghS[nxt][prow][pj2] = pg;
            }
        }
        __syncthreads();

        // ---- PH_D: gates reduce + LSTM + fused next-step decay ----
        if (tid < 256) {
            const int drow = tid >> 7, hj = tid & 127;
            float gi = blS[hj], gf = blS[128 + hj], gg = blS[256 + hj], go = blS[384 + hj];
#pragma unroll
            for (int k8 = 0; k8 < 8; ++k8) {
                gi += gp[k8][drow][hj];
                gf += gp[k8][drow][128 + hj];
                gg += gp[k8][drow][256 + hj];
                go += gp[k8][drow][384 + hj];
            }
            float cn = sigm(gf) * cs + sigm(gi) * tanhfast(gg);
            float hn = sigm(go) * tanhfast(cn);
            cs = cn;
            float gam;
            if (t == TT - 1) gam = 1.f;
            else {
                u32 gu = ghS[nxt][drow][hj >> 1];
                gam = (hj & 1) ? bfhi(gu) : bflo(gu);
            }
            float hd = hn * gam;
            float ho = __shfl_xor(hd, 1);
            if (!(hj & 1)) {
                ag2[drow][64 + (hj >> 1)] = pkh(hd, ho);
                float2 mv = *(const float2*)&mS[nxt][drow][hj];
                ag2[drow][128 + (hj >> 1)] = pkh(mv.x, mv.y);
            }
        }
        if (tid < 2) {
            float l = 0.f;
#pragma unroll
            for (int k8 = 0; k8 < 8; ++k8) l += slots1[tid * 8 + k8] + slots2[tid * 8 + k8];
            lossAcc[tid] += l * invdS[t];
        }
        __syncthreads();
    }

    // ---- predictions + custom_loss ----
    if (tid < 256) {
        int row = tid >> 7, jd = tid & 127;
        float acc = 0.f;
        for (int k2 = 0; k2 < 64; ++k2) {
            float2 hv = uph(ag2[row][64 + k2]);
            acc = fmaf(hv.x, Wd[(size_t)(2 * k2) * DD + jd], acc);
            acc = fmaf(hv.y, Wd[(size_t)(2 * k2 + 1) * DD + jd], acc);
        }
        float y = fmaxf(acc + bd[jd], 0.f) * Wo[jd];
#pragma unroll
        for (int off = 32; off; off >>= 1) y += __shfl_xor(y, off);
        if (lane == 0) predS[tid >> 6] = y;
    }
    __syncthreads();
    if (tid < 2) {
        out[b0 + tid] = predS[2 * tid] + predS[2 * tid + 1] + bo[0];
        out[512 + (size_t)BB * TT * DD + b0 + tid] = lossAcc[tid] * (1.f / TT);
    }
}

extern "C" void kernel_launch(void* const* d_in, const int* in_sizes, int n_in,
                              void* d_out, int out_size, void* d_ws, size_t ws_size,
                              hipStream_t stream) {
    const float* values = (const float*)d_in[0];
    const float* masks  = (const float*)d_in[1];
    const float* deltas = (const float*)d_in[2];
    const float* Wth = (const float*)d_in[3];
    const float* bth = (const float*)d_in[4];
    const float* Wtx = (const float*)d_in[5];
    const float* btx = (const float*)d_in[6];
    const float* Whr = (const float*)d_in[7];
    const float* bhr = (const float*)d_in[8];
    const float* Wfr = (const float*)d_in[9];
    const float* bfr = (const float*)d_in[10];
    const float* Wwc = (const float*)d_in[11];
    const float* bwc = (const float*)d_in[12];
    const float* Wk  = (const float*)d_in[13];
    const float* Wr  = (const float*)d_in[14];
    const float* bl  = (const float*)d_in[15];
    const float* Wd  = (const float*)d_in[16];
    const float* bd  = (const float*)d_in[17];
    const float* Wo  = (const float*)d_in[18];
    const float* bo  = (const float*)d_in[19];
    float* out = (float*)d_out;

    char* ws = (char*)d_ws;
    float* invden        = (float*)ws;                                  // 512 B
    __hip_bfloat16* gH   = (__hip_bfloat16*)(ws + 512);                 // 16 MiB
    __hip_bfloat16* beta = (__hip_bfloat16*)(ws + 512 + 16777216);      // 16 MiB
    u32* wp2             = (u32*)(ws + 512 + 2 * 16777216);             // 512 KiB (gates + pre)
    const u32* wpre1     = wp2 + 98304;
    const u32* wpre2     = wp2 + 114688;

    k_denom<<<TT, 256, 0, stream>>>(masks, invden);
    k_pack2<<<512, 256, 0, stream>>>(Wk, Wr, Wth, Wtx, Wwc, wp2);
    k_pre2<<<(BB * TT) / 32, 256, 0, stream>>>(masks, deltas, bth, btx, bwc,
                                               wpre1, wpre2, gH, beta);
    k_rnn3<<<BB / 2, 1024, 0, stream>>>(values, masks, Whr, bhr, Wfr, bfr, bl,
                                        Wd, bd, Wo, bo, invden, gH, beta, wp2, out);
}

// Round 12
// 908.904 us; speedup vs baseline: 3.3193x; 3.3193x over previous
//
#include <hip/hip_runtime.h>
#include <hip/hip_bf16.h>

#define BB 512
#define TT 128
#define DD 128
#define HH 128
#define EPSV 1e-6f

typedef _Float16 f16x2 __attribute__((ext_vector_type(2)));
typedef unsigned u32;

__device__ __forceinline__ float dot2f(u32 a, u32 b, float c) {
#if __has_builtin(__builtin_amdgcn_fdot2)
    return __builtin_amdgcn_fdot2(__builtin_bit_cast(f16x2, a),
                                  __builtin_bit_cast(f16x2, b), c, false);
#else
    f16x2 fa = __builtin_bit_cast(f16x2, a);
    f16x2 fb = __builtin_bit_cast(f16x2, b);
    return fmaf((float)fa.y, (float)fb.y, fmaf((float)fa.x, (float)fb.x, c));
#endif
}

__device__ __forceinline__ u32 pkh(float a, float b) {
    f16x2 v; v.x = (_Float16)a; v.y = (_Float16)b;
    return __builtin_bit_cast(u32, v);
}
__device__ __forceinline__ float2 uph(u32 u) {
    f16x2 v = __builtin_bit_cast(f16x2, u);
    return make_float2((float)v.x, (float)v.y);
}
__device__ __forceinline__ float bflo(u32 u) { return __builtin_bit_cast(float, u << 16); }
__device__ __forceinline__ float bfhi(u32 u) { return __builtin_bit_cast(float, u & 0xffff0000u); }
__device__ __forceinline__ float sigm(float x) { return 1.f / (1.f + __expf(-x)); }
__device__ __forceinline__ float tanhfast(float x) {
    float t = __expf(2.f * x);
    return 1.f - 2.f / (t + 1.f);
}

// ---------------- denom per timestep ----------------
__global__ __launch_bounds__(256) void k_denom(const float* __restrict__ masks,
                                               float* __restrict__ invden) {
    int t = blockIdx.x;
    float s = 0.f;
    for (int idx = threadIdx.x; idx < BB * 32; idx += 256) {
        int b = idx >> 5, q = idx & 31;
        float4 v = *(const float4*)(masks + ((size_t)b * TT + t) * DD + q * 4);
        s += v.x + v.y + v.z + v.w;
    }
    __shared__ float red[256];
    red[threadIdx.x] = s;
    __syncthreads();
    for (int off = 128; off > 0; off >>= 1) {
        if (threadIdx.x < off) red[threadIdx.x] += red[threadIdx.x + off];
        __syncthreads();
    }
    if (threadIdx.x == 0) invden[t] = 1.f / (red[0] + EPSV);
}

// ---------------- pack gates weights ([c_c;h] K=256) to fp16 pairs ----------------
// wp3 (65536 u32): thread t512=(kh*256+n0) of k_rnn4 loads 32 uint4 chunks:
//   u32 flat = (c*512 + t512)*4 + e ; r = c*4+e ; i = r>>1 (k-pair), ns = r&1
//   content = pair (W2[kh*128+2i][n0+ns*256], W2[kh*128+2i+1][same])
//   W2: k<128 -> Wk[k] (c_c part); else Wr[k-128] (h part)
__global__ __launch_bounds__(256) void k_pack3(const float* __restrict__ Wk,
                                               const float* __restrict__ Wr,
                                               u32* __restrict__ wp3) {
    int idx = blockIdx.x * 256 + threadIdx.x;   // 65536 total
    int e = idx & 3;
    int t = (idx >> 2) & 511;
    int c = idx >> 11;                          // 0..31
    int r = c * 4 + e;
    int i = r >> 1, ns = r & 1;
    int kh = t >> 8, n0 = t & 255;
    int n = n0 + ns * 256;
    int k0 = kh * 128 + 2 * i;
    float w0 = (k0 < 128) ? Wk[(size_t)k0 * 512 + n] : Wr[(size_t)(k0 - 128) * 512 + n];
    int k1 = k0 + 1;
    float w1 = (k1 < 128) ? Wk[(size_t)k1 * 512 + n] : Wr[(size_t)(k1 - 128) * 512 + n];
    wp3[idx] = pkh(w0, w1);
}

// ---------------- precompute gammaH, beta, gatesM for all (b,t) ----------------
__global__ __launch_bounds__(256) void k_pre(
    const float* __restrict__ masks, const float* __restrict__ deltas,
    const float* __restrict__ Wth, const float* __restrict__ bth,
    const float* __restrict__ Wtx, const float* __restrict__ btx,
    const float* __restrict__ Wwc, const float* __restrict__ bwc,
    const float* __restrict__ Wk, const float* __restrict__ bl,
    __hip_bfloat16* __restrict__ gH, __hip_bfloat16* __restrict__ beta,
    u32* __restrict__ gmP) {

    __shared__ __align__(16) float dT[32][128];   // reused as bpartS in stage 2
    __shared__ __align__(16) float mT[32][128];
    __shared__ __align__(16) float gx[32][128];

    const int tid = threadIdx.x;
    const int r0 = blockIdx.x * 32;

    {
        const float4* d4 = (const float4*)(deltas + (size_t)r0 * 128);
        const float4* m4 = (const float4*)(masks + (size_t)r0 * 128);
        float4* dT4 = (float4*)&dT[0][0];
        float4* mT4 = (float4*)&mT[0][0];
        for (int i = tid; i < 32 * 32; i += 256) { dT4[i] = d4[i]; mT4[i] = m4[i]; }
    }
    __syncthreads();

    // stage 1: gammaH (c<128) and gamma_x (c>=128)
    {
        const int c = tid;
        const float* Wrow = (c < 128) ? (Wth + (size_t)c * DD) : (Wtx + (size_t)(c - 128) * DD);
        const float bias = (c < 128) ? bth[c] : btx[c - 128];
        float acc[32];
#pragma unroll
        for (int r = 0; r < 32; ++r) acc[r] = 0.f;
        for (int k0 = 0; k0 < 128; k0 += 4) {
            float4 w = *(const float4*)(Wrow + k0);
#pragma unroll
            for (int r = 0; r < 32; ++r) {
                float4 a = *(const float4*)&dT[r][k0];
                acc[r] = fmaf(a.x, w.x, fmaf(a.y, w.y, fmaf(a.z, w.z, fmaf(a.w, w.w, acc[r]))));
            }
        }
#pragma unroll
        for (int r = 0; r < 32; ++r) {
            float v = __expf(-fmaxf(acc[r] + bias, 0.f));
            if (c < 128) gH[(size_t)(r0 + r) * 128 + c] = __float2bfloat16(v);
            else         gx[r][c - 128] = v;
        }
    }
    __syncthreads();

    // stage 2: beta = [gamma_x; m] @ Wwc + bwc (split-K across thread halves)
    {
        const int c = tid & 127, kh = tid >> 7;
        float acc[32];
#pragma unroll
        for (int r = 0; r < 32; ++r) acc[r] = 0.f;
        const float (*A2)[128] = (kh == 0) ? (const float (*)[128])gx : (const float (*)[128])mT;
        const float* wc = Wwc + (size_t)(kh * 128) * DD + c;
        for (int kk = 0; kk < 128; kk += 4) {
            float w0 = wc[(kk + 0) * DD], w1 = wc[(kk + 1) * DD];
            float w2 = wc[(kk + 2) * DD], w3 = wc[(kk + 3) * DD];
#pragma unroll
            for (int r = 0; r < 32; ++r) {
                float4 a = *(const float4*)&A2[r][kk];
                acc[r] = fmaf(a.x, w0, fmaf(a.y, w1, fmaf(a.z, w2, fmaf(a.w, w3, acc[r]))));
            }
        }
        float (*bpartS)[128] = dT;
        if (kh == 1) {
#pragma unroll
            for (int r = 0; r < 32; ++r) bpartS[r][c] = acc[r];
        }
        __syncthreads();
        if (kh == 0) {
            const float bb = bwc[c];
#pragma unroll
            for (int r = 0; r < 32; ++r) {
                float v = acc[r] + bpartS[r][c] + bb;
                beta[(size_t)(r0 + r) * 128 + c] = __float2bfloat16(v);
            }
        }
    }
    __syncthreads();

    // stage 3: gatesM = m @ Wk[128:256] + bl  -> fp16 pairs [row][256]
    {
        const int n0 = tid;                       // outputs n0 and n0+256
        const float blA = bl[n0], blB = bl[n0 + 256];
        for (int half = 0; half < 2; ++half) {
            float a0[16], a1[16];
#pragma unroll
            for (int r = 0; r < 16; ++r) { a0[r] = 0.f; a1[r] = 0.f; }
            for (int k = 0; k < 128; ++k) {
                float w0 = Wk[(size_t)(128 + k) * 512 + n0];
                float w1 = Wk[(size_t)(128 + k) * 512 + n0 + 256];
#pragma unroll
                for (int r = 0; r < 16; ++r) {
                    float mv = mT[half * 16 + r][k];
                    a0[r] = fmaf(mv, w0, a0[r]);
                    a1[r] = fmaf(mv, w1, a1[r]);
                }
            }
#pragma unroll
            for (int r = 0; r < 16; ++r) {
                float vA = a0[r] + blA, vB = a1[r] + blB;
                float voA = __shfl_xor(vA, 1), voB = __shfl_xor(vB, 1);
                if (!(tid & 1)) {
                    size_t base = (size_t)(r0 + half * 16 + r) * 256;
                    gmP[base + (n0 >> 1)]       = pkh(vA, voA);
                    gmP[base + 128 + (n0 >> 1)] = pkh(vB, voB);
                }
            }
        }
    }
}

// ---------------- recurrent kernel: 256 blocks x 2 rows x 512 threads ----------------
__global__ __launch_bounds__(512, 2) void k_rnn4(
    const float* __restrict__ values, const float* __restrict__ masks,
    const float* __restrict__ Whr, const float* __restrict__ bhr,
    const float* __restrict__ Wfr, const float* __restrict__ bfr,
    const float* __restrict__ Wd, const float* __restrict__ bd,
    const float* __restrict__ Wo, const float* __restrict__ bo,
    const float* __restrict__ invden,
    const __hip_bfloat16* __restrict__ gHws, const __hip_bfloat16* __restrict__ betws,
    const u32* __restrict__ gmP, const u32* __restrict__ wp3,
    float* __restrict__ out)
{
    const int tid = threadIdx.x;
    const int lane = tid & 63;
    const int w = tid >> 6;
    const int b0 = blockIdx.x * 2;

    __shared__ __align__(16) u32 whr2[128][68];
    __shared__ __align__(16) u32 wfr2[128][68];
    __shared__ __align__(16) u32 hp[2][64];       // decayed h pairs (fp16)
    __shared__ __align__(16) u32 cc2[2][64];      // c_c pairs
    __shared__ __align__(16) u32 xc2[2][64];      // x_c pairs
    __shared__ __align__(16) float gp[2][2][512]; // gates partials [kh][row][n]
    __shared__ __align__(16) float xS[2][2][128], mS[2][2][128];
    __shared__ __align__(16) u32 betS[2][2][64], ghS[2][2][64];
    __shared__ __align__(16) u32 gmS[2][2][256];  // gatesM fp16 pairs
    __shared__ float invdS[128], bhrS[128], bfrS[128];
    __shared__ float slots1[8], slots2[8];
    __shared__ float lossAcc[2];
    __shared__ float predS[4];

    // ---- gates weights into registers (128 u32 fp16 pairs) ----
    u32 wr_[128];
    {
        const uint4* wp4 = (const uint4*)wp3;
#pragma unroll
        for (int c = 0; c < 32; ++c) {
            uint4 q = wp4[c * 512 + tid];
            wr_[c * 4 + 0] = q.x; wr_[c * 4 + 1] = q.y;
            wr_[c * 4 + 2] = q.z; wr_[c * 4 + 3] = q.w;
        }
    }
    // ---- stage Whr / Wfr as fp16 k-pairs in LDS ----
    for (int idx = tid; idx < 8192; idx += 512) {
        int k2 = idx >> 7, j = idx & 127;
        whr2[j][k2] = pkh(Whr[(size_t)(2 * k2) * DD + j], Whr[(size_t)(2 * k2 + 1) * DD + j]);
    }
    for (int idx = tid; idx < 8192; idx += 512) {
        int j = idx >> 6, k2 = idx & 63;
        float2 wv = *(const float2*)&Wfr[(size_t)j * DD + 2 * k2];
        wfr2[j][k2] = pkh(wv.x, wv.y);
    }
    if (tid < 128) { invdS[tid] = invden[tid]; bhrS[tid] = bhr[tid]; bfrS[tid] = bfr[tid]; }
    if (tid < 128) {
        int prow = tid >> 6, pj2 = tid & 63;
        size_t r2 = ((size_t)(b0 + prow) * TT + 0) * DD + 2 * pj2;
        float2 px = *(const float2*)(values + r2);
        float2 pm = *(const float2*)(masks + r2);
        *(float2*)&xS[0][prow][2 * pj2] = px;
        *(float2*)&mS[0][prow][2 * pj2] = pm;
        betS[0][prow][pj2] = *(const u32*)(betws + r2);
        ghS[0][prow][pj2]  = *(const u32*)(gHws + r2);
        hp[prow][pj2] = 0u;                       // h = 0 (already "decayed")
    } else if (tid < 256) {
        int p = tid & 127, row = p >> 6, q = p & 63;
        ((uint4*)&gmS[0][row][0])[q] =
            ((const uint4*)gmP)[((size_t)(b0 + row) * TT + 0) * 64 + q];
    }
    if (tid < 2) lossAcc[tid] = 0.f;
    float cs = 0.f;                               // c state (tid<256 own it)
    __syncthreads();

    // GEMV coords: 8 waves; 4 waves per row; K split 2-way within wave
    const int grow = w >> 2, wj = w & 3;
    const int jj = lane & 31, kh2 = lane >> 5;
    const int j = wj * 32 + jj;
    // gates coords
    const int gkh = tid >> 8, gn0 = tid & 255;

    for (int t = 0; t < TT; ++t) {
        const int cur = t & 1, nxt = cur ^ 1;
        float xhat, xx, mm;

        // ---- PH1: xhat = h @ Whr ; pw1 ; publish x_c pairs ----
        {
            const uint4* wp = (const uint4*)&whr2[j][kh2 * 32];
            const uint4* ap = (const uint4*)&hp[grow][kh2 * 32];
            float s = 0.f;
#pragma unroll
            for (int c4 = 0; c4 < 8; ++c4) {
                uint4 wv = wp[c4]; uint4 av = ap[c4];
                s = dot2f(av.x, wv.x, s); s = dot2f(av.y, wv.y, s);
                s = dot2f(av.z, wv.z, s); s = dot2f(av.w, wv.w, s);
            }
            s += __shfl_xor(s, 32);
            xx = xS[cur][grow][j]; mm = mS[cur][grow][j];
            xhat = s + bhrS[j];
            float xcv = mm * xx + (1.f - mm) * xhat;
            float l = fabsf(xx - xhat) * mm;
            l += __shfl_xor(l, 16); l += __shfl_xor(l, 8);
            l += __shfl_xor(l, 4);  l += __shfl_xor(l, 2); l += __shfl_xor(l, 1);
            if (lane == 0) slots1[w] = l;
            float xo = __shfl_xor(xcv, 1);
            if (lane < 32 && !(lane & 1)) xc2[grow][wj * 16 + (lane >> 1)] = pkh(xcv, xo);
        }
        __syncthreads();

        // ---- PH2: zhat = x_c @ Wfr^T ; pw2 ; imputation ; publish c_c pairs ----
        {
            const uint4* wp = (const uint4*)&wfr2[j][kh2 * 32];
            const uint4* ap = (const uint4*)&xc2[grow][kh2 * 32];
            float s = 0.f;
#pragma unroll
            for (int c4 = 0; c4 < 8; ++c4) {
                uint4 wv = wp[c4]; uint4 av = ap[c4];
                s = dot2f(av.x, wv.x, s); s = dot2f(av.y, wv.y, s);
                s = dot2f(av.z, wv.z, s); s = dot2f(av.w, wv.w, s);
            }
            s += __shfl_xor(s, 32);
            float z = s + bfrS[j];
            u32 bu = betS[cur][grow][j >> 1];
            float be = (j & 1) ? bfhi(bu) : bflo(bu);
            float ch = be * z + (1.f - be) * xhat;
            float l = (fabsf(xx - z) + fabsf(xx - ch)) * mm;
            float ccv = mm * xx + (1.f - mm) * ch;
            if (lane < 32) out[512 + ((size_t)(b0 + grow) * TT + t) * DD + j] = ccv;
            l += __shfl_xor(l, 16); l += __shfl_xor(l, 8);
            l += __shfl_xor(l, 4);  l += __shfl_xor(l, 2); l += __shfl_xor(l, 1);
            if (lane == 0) slots2[w] = l;
            float co = __shfl_xor(ccv, 1);
            if (lane < 32 && !(lane & 1)) cc2[grow][wj * 16 + (lane >> 1)] = pkh(ccv, co);
        }
        __syncthreads();

        // ---- PH3: gates partials ([c_c;h] @ regs) + stream prefetch ----
        {
            float2 px, pm; u32 pb = 0, pg = 0; uint4 gq;
            const int tc = (t + 1 < TT) ? t + 1 : TT - 1;
            if (tid < 128) {
                int prow = tid >> 6, pj2 = tid & 63;
                size_t r2 = ((size_t)(b0 + prow) * TT + tc) * DD + 2 * pj2;
                px = *(const float2*)(values + r2);
                pm = *(const float2*)(masks + r2);
                pb = *(const u32*)(betws + r2);
                pg = *(const u32*)(gHws + r2);
            } else if (tid < 256) {
                int p = tid & 127, row = p >> 6, q = p & 63;
                gq = ((const uint4*)gmP)[((size_t)(b0 + row) * TT + tc) * 64 + q];
            }
            const u32* srcB = gkh ? &hp[0][0] : &cc2[0][0];
            const uint4* qaP = (const uint4*)srcB;          // row 0
            const uint4* qbP = (const uint4*)(srcB + 64);   // row 1
            float a00 = 0.f, a01 = 0.f, a10 = 0.f, a11 = 0.f;
#pragma unroll
            for (int c4 = 0; c4 < 16; ++c4) {
                uint4 ua = qaP[c4]; uint4 ub = qbP[c4];
#define GST(E, AV, BV)                                      \
                {                                           \
                    int i = c4 * 4 + (E);                   \
                    u32 w0 = wr_[i * 2], w1 = wr_[i * 2 + 1];\
                    a00 = dot2f((AV), w0, a00);             \
                    a01 = dot2f((AV), w1, a01);             \
                    a10 = dot2f((BV), w0, a10);             \
                    a11 = dot2f((BV), w1, a11);             \
                }
                GST(0, ua.x, ub.x)
                GST(1, ua.y, ub.y)
                GST(2, ua.z, ub.z)
                GST(3, ua.w, ub.w)
#undef GST
            }
            gp[gkh][0][gn0]       = a00; gp[gkh][0][gn0 + 256] = a01;
            gp[gkh][1][gn0]       = a10; gp[gkh][1][gn0 + 256] = a11;
            if (tid < 128) {
                int prow = tid >> 6, pj2 = tid & 63;
                *(float2*)&xS[nxt][prow][2 * pj2] = px;
                *(float2*)&mS[nxt][prow][2 * pj2] = pm;
                betS[nxt][prow][pj2] = pb;
                ghS[nxt][prow][pj2] = pg;
            } else if (tid < 256) {
                int p = tid & 127, row = p >> 6, q = p & 63;
                ((uint4*)&gmS[nxt][row][0])[q] = gq;
            }
        }
        __syncthreads();

        // ---- PH4: gates reduce + LSTM + fused next-step decay ----
        if (tid < 256) {
            const int row = tid >> 7, hj = tid & 127;
            const int h2 = hj >> 1, sel = hj & 1;
            float2 gI = uph(gmS[cur][row][h2]);
            float2 gF = uph(gmS[cur][row][64 + h2]);
            float2 gG = uph(gmS[cur][row][128 + h2]);
            float2 gO = uph(gmS[cur][row][192 + h2]);
            float gi = (sel ? gI.y : gI.x) + gp[0][row][hj]       + gp[1][row][hj];
            float gf = (sel ? gF.y : gF.x) + gp[0][row][128 + hj] + gp[1][row][128 + hj];
            float gg = (sel ? gG.y : gG.x) + gp[0][row][256 + hj] + gp[1][row][256 + hj];
            float go = (sel ? gO.y : gO.x) + gp[0][row][384 + hj] + gp[1][row][384 + hj];
            float cn = sigm(gf) * cs + sigm(gi) * tanhfast(gg);
            float hn = sigm(go) * tanhfast(cn);
            cs = cn;
            float gam;
            if (t == TT - 1) gam = 1.f;
            else {
                u32 gu = ghS[nxt][row][h2];
                gam = sel ? bfhi(gu) : bflo(gu);
            }
            float hd = hn * gam;
            float ho = __shfl_xor(hd, 1);
            if (!sel) hp[row][h2] = pkh(hd, ho);
        }
        if (tid < 2) {
            float l = 0.f;
#pragma unroll
            for (int q = 0; q < 4; ++q) l += slots1[tid * 4 + q] + slots2[tid * 4 + q];
            lossAcc[tid] += l * invdS[t];
        }
        __syncthreads();
    }

    // ---- predictions + custom_loss ----
    if (tid < 256) {
        int row = tid >> 7, jd = tid & 127;
        float acc = 0.f;
        for (int k2 = 0; k2 < 64; ++k2) {
            float2 hv = uph(hp[row][k2]);
            acc = fmaf(hv.x, Wd[(size_t)(2 * k2) * DD + jd], acc);
            acc = fmaf(hv.y, Wd[(size_t)(2 * k2 + 1) * DD + jd], acc);
        }
        float y = fmaxf(acc + bd[jd], 0.f) * Wo[jd];
#pragma unroll
        for (int off = 32; off; off >>= 1) y += __shfl_xor(y, off);
        if (lane == 0) predS[tid >> 6] = y;
    }
    __syncthreads();
    if (tid < 2) {
        out[b0 + tid] = predS[2 * tid] + predS[2 * tid + 1] + bo[0];
        out[512 + (size_t)BB * TT * DD + b0 + tid] = lossAcc[tid] * (1.f / TT);
    }
}

extern "C" void kernel_launch(void* const* d_in, const int* in_sizes, int n_in,
                              void* d_out, int out_size, void* d_ws, size_t ws_size,
                              hipStream_t stream) {
    const float* values = (const float*)d_in[0];
    const float* masks  = (const float*)d_in[1];
    const float* deltas = (const float*)d_in[2];
    const float* Wth = (const float*)d_in[3];
    const float* bth = (const float*)d_in[4];
    const float* Wtx = (const float*)d_in[5];
    const float* btx = (const float*)d_in[6];
    const float* Whr = (const float*)d_in[7];
    const float* bhr = (const float*)d_in[8];
    const float* Wfr = (const float*)d_in[9];
    const float* bfr = (const float*)d_in[10];
    const float* Wwc = (const float*)d_in[11];
    const float* bwc = (const float*)d_in[12];
    const float* Wk  = (const float*)d_in[13];
    const float* Wr  = (const float*)d_in[14];
    const float* bl  = (const float*)d_in[15];
    const float* Wd  = (const float*)d_in[16];
    const float* bd  = (const float*)d_in[17];
    const float* Wo  = (const float*)d_in[18];
    const float* bo  = (const float*)d_in[19];
    float* out = (float*)d_out;

    char* ws = (char*)d_ws;
    float* invden        = (float*)ws;                                   // 512 B
    __hip_bfloat16* gH   = (__hip_bfloat16*)(ws + 512);                  // 16 MiB
    __hip_bfloat16* beta = (__hip_bfloat16*)(ws + 512 + 16777216);       // 16 MiB
    u32* gmP             = (u32*)(ws + 512 + 2 * 16777216);              // 64 MiB
    u32* wp3             = (u32*)(ws + 512 + 2 * 16777216 + 67108864);   // 256 KiB

    k_denom<<<TT, 256, 0, stream>>>(masks, invden);
    k_pack3<<<256, 256, 0, stream>>>(Wk, Wr, wp3);
    k_pre<<<(BB * TT) / 32, 256, 0, stream>>>(masks, deltas, Wth, bth, Wtx, btx,
                                              Wwc, bwc, Wk, bl, gH, beta, gmP);
    k_rnn4<<<BB / 2, 512, 0, stream>>>(values, masks, Whr, bhr, Wfr, bfr,
                                       Wd, bd, Wo, bo, invden, gH, beta,
                                       gmP, wp3, out);
}